// Round 18
// baseline (264.423 us; speedup 1.0000x reference)
//
#include <hip/hip_runtime.h>
#include <hip/hip_bf16.h>

typedef __bf16 bf16_t;
typedef __bf16 bf16x8 __attribute__((ext_vector_type(8)));
typedef __bf16 bf16x4 __attribute__((ext_vector_type(4)));
typedef float  f32x4  __attribute__((ext_vector_type(4)));

#define LDS_DST(p) ((__attribute__((address_space(3))) void*)(p))
#define GLB_SRC(p) ((const __attribute__((address_space(1))) void*)(p))

#define SBAR()   asm volatile("s_barrier" ::: "memory")
#define WVM8()   asm volatile("s_waitcnt vmcnt(8)" ::: "memory")
#define WVM4()   asm volatile("s_waitcnt vmcnt(4)" ::: "memory")
#define WVM0()   asm volatile("s_waitcnt vmcnt(0)" ::: "memory")
#define SP1()    __builtin_amdgcn_s_setprio(1)
#define SP0()    __builtin_amdgcn_s_setprio(0)

// ============== fp32 -> bf16 converts, one launch, 4x float4/thread ==========
// flat ranges: [0,3072) q | [+3072) v | [+144) Wq | [+144) Wk | [+144) Wv
__global__ void __launch_bounds__(256)
convert_kernel(const float* __restrict__ q_in, const float* __restrict__ v_in,
               const float* __restrict__ wq_in, const float* __restrict__ wk_in,
               const float* __restrict__ wv_in,
               bf16_t* __restrict__ qb, bf16_t* __restrict__ vb,
               bf16_t* __restrict__ wqb, bf16_t* __restrict__ wkb,
               bf16_t* __restrict__ wvb) {
  const int tid = threadIdx.x;
  int r = blockIdx.x;
  const float* in; bf16_t* out; int base;
  if (r < 6144) {
    in = (r < 3072) ? q_in : v_in;
    out = (r < 3072) ? qb : vb;
    base = (r % 3072) * 1024;
  } else {
    r -= 6144;
    in = (r < 144) ? wq_in : (r < 288 ? wk_in : wv_in);
    out = (r < 144) ? wqb : (r < 288 ? wkb : wvb);
    base = (r % 144) * 1024;
  }
#pragma unroll
  for (int j = 0; j < 4; ++j) {
    const int i = base + j * 256 + tid;
    const float4 v = reinterpret_cast<const float4*>(in)[i];
    bf16x4 o;
    o[0] = (bf16_t)v.x; o[1] = (bf16_t)v.y; o[2] = (bf16_t)v.z; o[3] = (bf16_t)v.w;
    reinterpret_cast<bf16x4*>(out)[i] = o;
  }
}

// ========== 256x256 GEMM, 2 merged phases per K-tile, counted vmcnt ==========
// (R11 main-loop configuration -- best measured. Hazard map: see R7 notes.)
// R18: MODE 3 = k-proj + transpose heterogeneous launch (256 flat blocks):
// f1<192 -> k-proj role (decode identical to old 64x3 by-major launch);
// f1>=192 -> transpose role (64 blocks x 48 tiles of 64x64, vp->vpT), filling
// the 64 CUs the 192-block k-proj left idle. XCD chunking puts transpose
// blocks on XCDs 6-7 (clean L2 partition). Standalone transpose kernel gone.
// REGISTER BUDGET (hard limit, learned R6): acc 128 AGPR + <=16 live frags in
// main loop; epilogue reuses freed frag regs (2x32 VGPR mask buffers ok).

__device__ __forceinline__ void read_A(const char* smem, int off, bf16x8 (&af)[8], int xk0) {
#pragma unroll
  for (int mf = 0; mf < 4; ++mf)
#pragma unroll
    for (int kk = 0; kk < 2; ++kk)
      af[mf * 2 + kk] = *reinterpret_cast<const bf16x8*>(
          smem + off + mf * 2048 + (kk ? (xk0 ^ 64) : xk0));
}

__device__ __forceinline__ void read_B(const char* smem, int off, bf16x8 (&bf_)[4], int xk0) {
#pragma unroll
  for (int nf = 0; nf < 2; ++nf)
#pragma unroll
    for (int kk = 0; kk < 2; ++kk)
      bf_[nf * 2 + kk] = *reinterpret_cast<const bf16x8*>(
          smem + off + nf * 2048 + (kk ? (xk0 ^ 64) : xk0));
}

template <int MH, int NH>
__device__ __forceinline__ void mfma_q(const bf16x8 (&af)[8], const bf16x8 (&bf_)[4],
                                       f32x4 (&acc)[8][4]) {
#pragma unroll
  for (int mf = 0; mf < 4; ++mf)
#pragma unroll
    for (int nf = 0; nf < 2; ++nf)
#pragma unroll
      for (int kk = 0; kk < 2; ++kk)
        acc[MH * 4 + mf][NH * 2 + nf] = __builtin_amdgcn_mfma_f32_16x16x32_bf16(
            af[mf * 2 + kk], bf_[nf * 2 + kk], acc[MH * 4 + mf][NH * 2 + nf], 0, 0, 0);
}

#define STAGE_A(slot, mh, kt) do {                                            \
  _Pragma("unroll") for (int j_ = 0; j_ < 2; ++j_)                            \
    __builtin_amdgcn_global_load_lds(                                         \
        GLB_SRC(pA + (long)(j_ * 128 + (mh) * 64) * K + (kt)),                \
        LDS_DST(smem + (slot) * 65536 + (arow0 + j_ * 128 + (mh) * 64) * 128),\
        16, 0, 0);                                                            \
} while (0)

#define STAGE_B(slot, nh, kt) do {                                            \
  _Pragma("unroll") for (int j_ = 0; j_ < 2; ++j_)                            \
    __builtin_amdgcn_global_load_lds(                                         \
        GLB_SRC(pB + (long)(j_ * 128 + (nh) * 32) * K + (kt)),                \
        LDS_DST(smem + (slot) * 65536 + 32768 +                               \
                (brow0 + j_ * 128 + (nh) * 32) * 128),                        \
        16, 0, 0);                                                            \
} while (0)

// write acc round RD (compile-time) into chunk buffer eb (64 rows x 256 cols)
#define EWRITE(RD, eb) do {                                                   \
  _Pragma("unroll") for (int fi = 0; fi < 2; ++fi)                            \
  _Pragma("unroll") for (int nf = 0; nf < 4; ++nf)                            \
  _Pragma("unroll") for (int r = 0; r < 4; ++r) {                             \
    const int lr2 = wr * 32 + fi * 16 + lg * 4 + r;                           \
    (eb)[lr2 * 256 + wc * 64 + nf * 16 + l15] = acc[(RD) * 2 + fi][nf][r];    \
  }                                                                           \
} while (0)

// MODE 0: bf16 out = acc + bias[n] (z=1 uses alt pointer set A2/B2/bias2/C2)
// MODE 1: bf16 out = mask ? sigmoid(acc) : 0 (mask read int32, direct)
// MODE 2: f32 out = acc
// MODE 3: k-proj (as MODE 0, single pointer set) + transpose role (vp->C2^T)
template <int MODE>
__global__ void __launch_bounds__(512, 2)
gemm8p_kernel(const bf16_t* __restrict__ A, const bf16_t* __restrict__ B,
              const float* __restrict__ bias, const int* __restrict__ mask,
              void* __restrict__ Cout, int M, int N, int K,
              long sA, long sB, long sC, long sMask,
              const bf16_t* __restrict__ A2, const bf16_t* __restrict__ B2,
              const float* __restrict__ bias2, void* __restrict__ C2) {
  __shared__ __align__(1024) char smem[131072];
  constexpr int EM = (MODE == 3) ? 0 : MODE;

  // ---- bijective XCD chunking (m204) + supertile decode (R9) ----
  const int gx = gridDim.x, gy = gridDim.y;
  int f0 = blockIdx.x + gx * (blockIdx.y + gy * blockIdx.z);
  const int nwg = gx * gy * (int)gridDim.z;
  const int q8 = nwg >> 3, r8 = nwg & 7;
  const int xcd = f0 & 7, idx = f0 >> 3;
  int f1 = (xcd < r8 ? xcd * (q8 + 1) : r8 * (q8 + 1) + (xcd - r8) * q8) + idx;
  int bxi, byi, bz;
  if constexpr (MODE == 3) {
    // 256 flat blocks: f1 < 192 k-proj (by-major, same map as old 64x3
    // launch: byi=f1%3, bxi=f1/3); f1 >= 192: transpose role.
    if (f1 >= 192) {
      // ---- transpose role: 48 tiles of 64x64, vp (A) -> vpT (C2) ----
      bf16_t (*tile)[72] = (bf16_t(*)[72])smem;
      bf16_t* vpT = (bf16_t*)C2;
      const int tid_ = threadIdx.x;
      const int rr = tid_ >> 3, cg = tid_ & 7;   // rr 0..63, cg 0..7
      const int tt = f1 - 192;
      for (int i = 0; i < 48; ++i) {
        const int tau = tt * 48 + i;             // 0..3071
        const int z = tau / 384, rem = tau % 384;
        const int rx = rem % 32, cy = rem / 32;  // r-tile 0..31, c-tile 0..11
        const long base = (long)z * 2048 * 768;
        const bf16_t* ib = A + base;             // vp[z]
        bf16_t* ob = vpT + base;
        const int r0 = rx * 64, c0 = cy * 64;
        __syncthreads();                         // tile reuse across i
        *reinterpret_cast<bf16x8*>(&tile[rr][cg * 8]) =
            *reinterpret_cast<const bf16x8*>(ib + (long)(r0 + rr) * 768 + c0 + cg * 8);
        __syncthreads();
        bf16x8 v;
#pragma unroll
        for (int e = 0; e < 8; ++e) v[e] = tile[cg * 8 + e][rr];
        *reinterpret_cast<bf16x8*>(ob + (long)(c0 + rr) * 2048 + r0 + cg * 8) = v;
      }
      return;
    }
    byi = f1 % 3;
    bxi = f1 / 3;
    bz = 0;
  } else if constexpr (MODE == 1) {
    // supertile = 8bx x 2by; f1 = bx + 8*(by&1) + 16*((by>>1) + 4*bz)
    bxi = f1 & 7;
    const int byL = (f1 >> 3) & 1;
    const int st = (f1 >> 4) & 3;
    bz = f1 >> 6;
    byi = st * 2 + byL;
  } else {
    // by-major: f1 = by + gy*(bx + gx*bz)
    byi = f1 % gy;
    const int t = f1 / gy;
    bxi = t % gx;
    bz = t / gx;
  }

  const bf16_t* Ab; const bf16_t* Bb;
  const float* biasp = bias; void* Cp = Cout;
  if constexpr (EM == 0) {
    if (MODE == 0 && bz) { Ab = A2; Bb = B2; biasp = bias2; Cp = C2; }
    else                 { Ab = A;  Bb = B; }
  } else {
    Ab = A + bz * sA; Bb = B + bz * sB;
  }
  const int bm = bxi * 256, bn = byi * 256;
  const int tid = threadIdx.x;
  const int wave = tid >> 6, lane = tid & 63;
  const int wr = wave >> 2, wc = wave & 3;
  const int l15 = lane & 15, lg = lane >> 4;
  const int xk0 = (lg * 16) ^ ((lane & 7) << 4);
  const int NT = K >> 6;

  // staging bases
  const int lr = lane >> 3;
  const int cgs = ((lane & 7) ^ lr) * 8;
  const int arow0 = wave * 8;
  const int brow0 = (wave >> 2) * 64 + (wave & 3) * 8;
  const bf16_t* pA = Ab + (long)(bm + arow0 + lr) * K + cgs;
  const bf16_t* pB = Bb + (long)(bn + brow0 + lr) * K + cgs;

  // ds_read base offsets
  const int aoff = wr * 16384 + l15 * 128;          // + slot*65536 + mh*8192
  const int boff = 32768 + wc * 8192 + l15 * 128;   // + slot*65536 + nh*4096

  f32x4 acc[8][4] = {};
  bf16x8 afX[8], bfB[4], bf0[4];

  // ---- prologue: t0 full (8 instrs), then A0/B0(1) (4), B1/A1(1) (4) ----
  STAGE_A(0, 0, 0); STAGE_B(0, 0, 0); STAGE_B(0, 1, 0); STAGE_A(0, 1, 0);
  STAGE_A(1, 0, 64); STAGE_B(1, 0, 64);
  STAGE_B(1, 1, 64); STAGE_A(1, 1, 64);
  WVM8();   // tile0's 8 instrs landed
  SBAR();
  read_A(smem, aoff + 0, afX, xk0);   // A0(t0)
  read_B(smem, boff + 0, bf0, xk0);   // B0(t0)

  int slot = 0;
  for (int t = 0; t + 2 < NT; ++t) {
    const int so = slot * 65536, sn = (slot ^ 1) * 65536;
    const int k2 = (t + 2) << 6;
    // ---- P_a ----
    read_B(smem, so + boff + 4096, bfB, xk0);        // B1(t)
    STAGE_A(slot, 0, k2); STAGE_B(slot, 0, k2);      // A0(t+2), B0(t+2)
    SP1(); mfma_q<0, 0>(afX, bf0, acc); SP0();
    SP1(); mfma_q<0, 1>(afX, bfB, acc); SP0();
    read_A(smem, so + aoff + 8192, afX, xk0);        // A1(t)
    WVM8(); SBAR();                                  // c1
    // ---- P_b ----
    SP1(); mfma_q<1, 1>(afX, bfB, acc); SP0();
    SP1(); mfma_q<1, 0>(afX, bf0, acc); SP0();
    read_A(smem, sn + aoff + 0, afX, xk0);           // A0(t+1)
    read_B(smem, sn + boff + 0, bf0, xk0);           // B0(t+1)
    STAGE_B(slot, 1, k2); STAGE_A(slot, 1, k2);      // B1(t+2), A1(t+2)
    WVM8(); SBAR();                                  // c2
    slot ^= 1;
  }

  // ---- drain: tiles NT-2 (so), NT-1 (sn); no staging ----
  {
    const int so = slot * 65536, sn = (slot ^ 1) * 65536;
    read_B(smem, so + boff + 4096, bfB, xk0);        // B1(NT-2)
    SP1(); mfma_q<0, 0>(afX, bf0, acc); SP0();
    SP1(); mfma_q<0, 1>(afX, bfB, acc); SP0();
    read_A(smem, so + aoff + 8192, afX, xk0);        // A1(NT-2)
    WVM4(); SBAR();
    SP1(); mfma_q<1, 1>(afX, bfB, acc); SP0();
    SP1(); mfma_q<1, 0>(afX, bf0, acc); SP0();
    read_A(smem, sn + aoff + 0, afX, xk0);           // A0(NT-1)
    read_B(smem, sn + boff + 0, bf0, xk0);           // B0(NT-1)
    WVM0(); SBAR();
    // last tile
    read_B(smem, sn + boff + 4096, bfB, xk0);        // B1(NT-1)
    SP1(); mfma_q<0, 0>(afX, bf0, acc); SP0();
    SP1(); mfma_q<0, 1>(afX, bfB, acc); SP0();
    read_A(smem, sn + aoff + 8192, afX, xk0);        // A1(NT-1)
    SP1(); mfma_q<1, 1>(afX, bfB, acc); SP0();
    SP1(); mfma_q<1, 0>(afX, bf0, acc); SP0();
  }

  // ---- C-write: 4 rounds, double-buffered 64KB chunks, 1 barrier/round ----
  // (fully unrolled: acc/mask indices compile-time -- rule #20)
  float* eb0 = (float*)smem;
  float* eb1 = (float*)(smem + 65536);
  const int lrow = tid >> 3, t7 = tid & 7;
  const int growt0 = lrow + ((lrow >> 5) * 96);      // row map (wr0|wr1 halves)
  int4 m4a[8], m4b[8];
  if constexpr (EM == 1) {
    const int* mrow = mask + bz * sMask + (long)(bm + growt0) * N + bn;
#pragma unroll
    for (int q = 0; q < 8; ++q)
      m4a[q] = *reinterpret_cast<const int4*>(mrow + (q * 8 + t7) * 4);
  }
  EWRITE(0, eb0);
  __syncthreads();
#pragma unroll
  for (int rd = 0; rd < 4; ++rd) {
    // prefetch next round's mask (uses the buffer NOT consumed this round)
    if constexpr (EM == 1) {
      if (rd < 3) {
        const int* mrow =
            mask + bz * sMask + (long)(bm + (rd + 1) * 32 + growt0) * N + bn;
        if ((rd & 1) == 0) {
#pragma unroll
          for (int q = 0; q < 8; ++q)
            m4b[q] = *reinterpret_cast<const int4*>(mrow + (q * 8 + t7) * 4);
        } else {
#pragma unroll
          for (int q = 0; q < 8; ++q)
            m4a[q] = *reinterpret_cast<const int4*>(mrow + (q * 8 + t7) * 4);
        }
      }
    }
    // stage next round's acc into the other buffer (overlaps with emission)
    if (rd < 3) {
      if ((rd & 1) == 0) { EWRITE(rd + 1, eb1); } else { EWRITE(rd + 1, eb0); }
    }
    // emit this round from its buffer
    const float* eb = ((rd & 1) == 0) ? eb0 : eb1;
    const long rowbase = (long)(bm + rd * 32 + growt0) * N + bn;
#pragma unroll
    for (int q = 0; q < 8; ++q) {
      const int c4 = (q * 8 + t7) * 4;
      const f32x4 v = *reinterpret_cast<const f32x4*>(&eb[lrow * 256 + c4]);
      if constexpr (EM == 1) {
        const int4 mq = ((rd & 1) == 0) ? m4a[q] : m4b[q];
        bf16x4 o;
        o[0] = (bf16_t)(mq.x ? __builtin_amdgcn_rcpf(1.f + __expf(-v[0])) : 0.f);
        o[1] = (bf16_t)(mq.y ? __builtin_amdgcn_rcpf(1.f + __expf(-v[1])) : 0.f);
        o[2] = (bf16_t)(mq.z ? __builtin_amdgcn_rcpf(1.f + __expf(-v[2])) : 0.f);
        o[3] = (bf16_t)(mq.w ? __builtin_amdgcn_rcpf(1.f + __expf(-v[3])) : 0.f);
        *reinterpret_cast<bf16x4*>((bf16_t*)Cp + bz * sC + rowbase + c4) = o;
      } else if constexpr (EM == 0) {
        const f32x4 b4 = *reinterpret_cast<const f32x4*>(biasp + bn + c4);
        bf16x4 o;
        o[0] = (bf16_t)(v[0] + b4[0]); o[1] = (bf16_t)(v[1] + b4[1]);
        o[2] = (bf16_t)(v[2] + b4[2]); o[3] = (bf16_t)(v[3] + b4[3]);
        *reinterpret_cast<bf16x4*>((bf16_t*)Cp + bz * sC + rowbase + c4) = o;
      } else {
        *reinterpret_cast<f32x4*>((float*)Cp + bz * sC + rowbase + c4) = v;
      }
    }
    __syncthreads();   // protects: reads of this buffer done before rd+2 write
  }
}

extern "C" void kernel_launch(void* const* d_in, const int* in_sizes, int n_in,
                              void* d_out, int out_size, void* d_ws, size_t ws_size,
                              hipStream_t stream) {
  const float* queries = (const float*)d_in[0];
  const float* values  = (const float*)d_in[1];
  const int*   mask    = (const int*)d_in[2];
  const float* Wq = (const float*)d_in[3];
  const float* bq = (const float*)d_in[4];
  const float* Wk = (const float*)d_in[5];
  const float* bk = (const float*)d_in[6];
  const float* Wv = (const float*)d_in[7];
  const float* bv = (const float*)d_in[8];

  // B=8, L=2048, D=768. Workspace layout (bytes):
  char* ws = (char*)d_ws;
  bf16_t* qb  = (bf16_t*)(ws + 0);          // queries bf16   25165824
  bf16_t* vb  = (bf16_t*)(ws + 25165824);   // values bf16    25165824
  bf16_t* wqb = (bf16_t*)(ws + 50331648);   // Wq bf16         1179648
  bf16_t* wkb = (bf16_t*)(ws + 51511296);   // Wk bf16         1179648
  bf16_t* wvb = (bf16_t*)(ws + 52690944);   // Wv bf16         1179648
  bf16_t* qp  = (bf16_t*)(ws + 53870592);   // q_proj         25165824
  bf16_t* vp  = (bf16_t*)(ws + 79036416);   // v_proj         25165824
  bf16_t* kp  = (bf16_t*)(ws + 104202240);  // k_proj         25165824
  bf16_t* vpT = (bf16_t*)(ws + 129368064);  // v_proj^T       25165824
  bf16_t* P   = (bf16_t*)(ws + 154533888);  // sigmoid scores 67108864
  // total: 221642752

  // converts (q, v, 3 weights) in one launch, 4 float4/thread
  convert_kernel<<<6576, 256, 0, stream>>>(queries, values, Wq, Wk, Wv,
                                           qb, vb, wqb, wkb, wvb);

  const dim3 blk2(512);

  // q-proj & v-proj batched (independent): z=0 qb*Wq+bq->qp, z=1 vb*Wv+bv->vp
  gemm8p_kernel<0><<<dim3(64, 3, 2), blk2, 0, stream>>>(
      qb, wqb, bq, nullptr, qp, 16384, 768, 768, 0, 0, 0, 0,
      vb, wvb, bv, vp);
  // k-proj (faithful quirk: k = Linear_k(v_proj)) + transpose vp->vpT fused
  // as heterogeneous roles in one 256-block launch (R18).
  gemm8p_kernel<3><<<dim3(256, 1, 1), blk2, 0, stream>>>(
      vp, wkb, bk, nullptr, kp, 16384, 768, 768, 0, 0, 0, 0,
      nullptr, nullptr, nullptr, vpT);

  // P = sigmoid(mask(q k^T)) : per batch [2048,2048], K=768; int32 mask direct
  gemm8p_kernel<1><<<dim3(8, 8, 8), blk2, 0, stream>>>(
      qp, kp, nullptr, mask, P, 2048, 2048, 768,
      (long)2048 * 768, (long)2048 * 768, (long)2048 * 2048, (long)2048 * 2048,
      nullptr, nullptr, nullptr, nullptr);

  // context = P v : per batch [2048,768], K=2048, fp32 out
  gemm8p_kernel<2><<<dim3(8, 3, 8), blk2, 0, stream>>>(
      P, vpT, nullptr, nullptr, d_out, 2048, 768, 2048,
      (long)2048 * 2048, (long)768 * 2048, (long)2048 * 768, 0,
      nullptr, nullptr, nullptr, nullptr);
}

// Round 19
// 253.544 us; speedup vs baseline: 1.0429x; 1.0429x over previous
//
#include <hip/hip_runtime.h>
#include <hip/hip_bf16.h>

typedef __bf16 bf16_t;
typedef __bf16 bf16x8 __attribute__((ext_vector_type(8)));
typedef __bf16 bf16x4 __attribute__((ext_vector_type(4)));
typedef float  f32x4  __attribute__((ext_vector_type(4)));

#define LDS_DST(p) ((__attribute__((address_space(3))) void*)(p))
#define GLB_SRC(p) ((const __attribute__((address_space(1))) void*)(p))

#define SBAR()   asm volatile("s_barrier" ::: "memory")
#define WVM8()   asm volatile("s_waitcnt vmcnt(8)" ::: "memory")
#define WVM4()   asm volatile("s_waitcnt vmcnt(4)" ::: "memory")
#define WVM0()   asm volatile("s_waitcnt vmcnt(0)" ::: "memory")
#define SP1()    __builtin_amdgcn_s_setprio(1)
#define SP0()    __builtin_amdgcn_s_setprio(0)

// ============== fp32 -> bf16 converts, one launch, 4x float4/thread ==========
// flat ranges: [0,3072) q | [+3072) v | [+144) Wq | [+144) Wk | [+144) Wv
__global__ void __launch_bounds__(256)
convert_kernel(const float* __restrict__ q_in, const float* __restrict__ v_in,
               const float* __restrict__ wq_in, const float* __restrict__ wk_in,
               const float* __restrict__ wv_in,
               bf16_t* __restrict__ qb, bf16_t* __restrict__ vb,
               bf16_t* __restrict__ wqb, bf16_t* __restrict__ wkb,
               bf16_t* __restrict__ wvb) {
  const int tid = threadIdx.x;
  int r = blockIdx.x;
  const float* in; bf16_t* out; int base;
  if (r < 6144) {
    in = (r < 3072) ? q_in : v_in;
    out = (r < 3072) ? qb : vb;
    base = (r % 3072) * 1024;
  } else {
    r -= 6144;
    in = (r < 144) ? wq_in : (r < 288 ? wk_in : wv_in);
    out = (r < 144) ? wqb : (r < 288 ? wkb : wvb);
    base = (r % 144) * 1024;
  }
#pragma unroll
  for (int j = 0; j < 4; ++j) {
    const int i = base + j * 256 + tid;
    const float4 v = reinterpret_cast<const float4*>(in)[i];
    bf16x4 o;
    o[0] = (bf16_t)v.x; o[1] = (bf16_t)v.y; o[2] = (bf16_t)v.z; o[3] = (bf16_t)v.w;
    reinterpret_cast<bf16x4*>(out)[i] = o;
  }
}

// ---------------- bf16 transpose: in [z][R][C] -> out [z][C][R] ----------------
__global__ void __launch_bounds__(256)
transpose_bf16_kernel(const bf16_t* __restrict__ in, bf16_t* __restrict__ out,
                      int R, int C) {
  __shared__ bf16_t tile[64][72];
  const long base = (long)blockIdx.z * R * C;
  const bf16_t* ib = in + base;
  bf16_t* ob = out + base;
  const int r0 = blockIdx.x * 64, c0 = blockIdx.y * 64;
  const int tid = threadIdx.x;
  const int rr = tid >> 3, cg = tid & 7;
#pragma unroll
  for (int p = 0; p < 2; ++p) {
    int row = p * 32 + rr;
    bf16x8 v = *reinterpret_cast<const bf16x8*>(ib + (long)(r0 + row) * C + c0 + cg * 8);
    *reinterpret_cast<bf16x8*>(&tile[row][cg * 8]) = v;
  }
  __syncthreads();
#pragma unroll
  for (int p = 0; p < 2; ++p) {
    int c = p * 32 + rr;
    bf16x8 v;
#pragma unroll
    for (int i = 0; i < 8; ++i) v[i] = tile[cg * 8 + i][c];
    *reinterpret_cast<bf16x8*>(ob + (long)(c0 + c) * R + r0 + cg * 8) = v;
  }
}

// ========== 256x256 GEMM, 2 merged phases per K-tile, counted vmcnt ==========
// (R11/R17 configuration -- best measured, 253.4us. Hazard map: see R7 notes.)
// REGISTER BUDGET (hard limit, learned R6): acc 128 AGPR + <=16 live frags in
// main loop; epilogue reuses freed frag regs (2x32 VGPR mask buffers ok).

__device__ __forceinline__ void read_A(const char* smem, int off, bf16x8 (&af)[8], int xk0) {
#pragma unroll
  for (int mf = 0; mf < 4; ++mf)
#pragma unroll
    for (int kk = 0; kk < 2; ++kk)
      af[mf * 2 + kk] = *reinterpret_cast<const bf16x8*>(
          smem + off + mf * 2048 + (kk ? (xk0 ^ 64) : xk0));
}

__device__ __forceinline__ void read_B(const char* smem, int off, bf16x8 (&bf_)[4], int xk0) {
#pragma unroll
  for (int nf = 0; nf < 2; ++nf)
#pragma unroll
    for (int kk = 0; kk < 2; ++kk)
      bf_[nf * 2 + kk] = *reinterpret_cast<const bf16x8*>(
          smem + off + nf * 2048 + (kk ? (xk0 ^ 64) : xk0));
}

template <int MH, int NH>
__device__ __forceinline__ void mfma_q(const bf16x8 (&af)[8], const bf16x8 (&bf_)[4],
                                       f32x4 (&acc)[8][4]) {
#pragma unroll
  for (int mf = 0; mf < 4; ++mf)
#pragma unroll
    for (int nf = 0; nf < 2; ++nf)
#pragma unroll
      for (int kk = 0; kk < 2; ++kk)
        acc[MH * 4 + mf][NH * 2 + nf] = __builtin_amdgcn_mfma_f32_16x16x32_bf16(
            af[mf * 2 + kk], bf_[nf * 2 + kk], acc[MH * 4 + mf][NH * 2 + nf], 0, 0, 0);
}

#define STAGE_A(slot, mh, kt) do {                                            \
  _Pragma("unroll") for (int j_ = 0; j_ < 2; ++j_)                            \
    __builtin_amdgcn_global_load_lds(                                         \
        GLB_SRC(pA + (long)(j_ * 128 + (mh) * 64) * K + (kt)),                \
        LDS_DST(smem + (slot) * 65536 + (arow0 + j_ * 128 + (mh) * 64) * 128),\
        16, 0, 0);                                                            \
} while (0)

#define STAGE_B(slot, nh, kt) do {                                            \
  _Pragma("unroll") for (int j_ = 0; j_ < 2; ++j_)                            \
    __builtin_amdgcn_global_load_lds(                                         \
        GLB_SRC(pB + (long)(j_ * 128 + (nh) * 32) * K + (kt)),                \
        LDS_DST(smem + (slot) * 65536 + 32768 +                               \
                (brow0 + j_ * 128 + (nh) * 32) * 128),                        \
        16, 0, 0);                                                            \
} while (0)

// write acc round RD (compile-time) into chunk buffer eb (64 rows x 256 cols)
#define EWRITE(RD, eb) do {                                                   \
  _Pragma("unroll") for (int fi = 0; fi < 2; ++fi)                            \
  _Pragma("unroll") for (int nf = 0; nf < 4; ++nf)                            \
  _Pragma("unroll") for (int r = 0; r < 4; ++r) {                             \
    const int lr2 = wr * 32 + fi * 16 + lg * 4 + r;                           \
    (eb)[lr2 * 256 + wc * 64 + nf * 16 + l15] = acc[(RD) * 2 + fi][nf][r];    \
  }                                                                           \
} while (0)

// MODE 0: bf16 out = acc + bias[n] (z=1 uses alt pointer set A2/B2/bias2/C2)
// MODE 1: bf16 out = mask ? sigmoid(acc) : 0 (mask read int32, direct)
// MODE 2: f32 out = acc
template <int MODE>
__global__ void __launch_bounds__(512, 2)
gemm8p_kernel(const bf16_t* __restrict__ A, const bf16_t* __restrict__ B,
              const float* __restrict__ bias, const int* __restrict__ mask,
              void* __restrict__ Cout, int M, int N, int K,
              long sA, long sB, long sC, long sMask,
              const bf16_t* __restrict__ A2, const bf16_t* __restrict__ B2,
              const float* __restrict__ bias2, void* __restrict__ C2) {
  __shared__ __align__(1024) char smem[131072];

  // ---- bijective XCD chunking (m204) + supertile decode (R9) ----
  const int gx = gridDim.x, gy = gridDim.y;
  int f0 = blockIdx.x + gx * (blockIdx.y + gy * blockIdx.z);
  const int nwg = gx * gy * (int)gridDim.z;
  const int q8 = nwg >> 3, r8 = nwg & 7;
  const int xcd = f0 & 7, idx = f0 >> 3;
  int f1 = (xcd < r8 ? xcd * (q8 + 1) : r8 * (q8 + 1) + (xcd - r8) * q8) + idx;
  int bxi, byi, bz;
  if constexpr (MODE == 1) {
    // supertile = 8bx x 2by; f1 = bx + 8*(by&1) + 16*((by>>1) + 4*bz)
    bxi = f1 & 7;
    const int byL = (f1 >> 3) & 1;
    const int st = (f1 >> 4) & 3;
    bz = f1 >> 6;
    byi = st * 2 + byL;
  } else {
    // by-major: f1 = by + gy*(bx + gx*bz)
    byi = f1 % gy;
    const int t = f1 / gy;
    bxi = t % gx;
    bz = t / gx;
  }

  const bf16_t* Ab; const bf16_t* Bb;
  const float* biasp = bias; void* Cp = Cout;
  if constexpr (MODE == 0) {
    if (bz) { Ab = A2; Bb = B2; biasp = bias2; Cp = C2; }
    else    { Ab = A;  Bb = B; }
  } else {
    Ab = A + bz * sA; Bb = B + bz * sB;
  }
  const int bm = bxi * 256, bn = byi * 256;
  const int tid = threadIdx.x;
  const int wave = tid >> 6, lane = tid & 63;
  const int wr = wave >> 2, wc = wave & 3;
  const int l15 = lane & 15, lg = lane >> 4;
  const int xk0 = (lg * 16) ^ ((lane & 7) << 4);
  const int NT = K >> 6;

  // staging bases
  const int lr = lane >> 3;
  const int cgs = ((lane & 7) ^ lr) * 8;
  const int arow0 = wave * 8;
  const int brow0 = (wave >> 2) * 64 + (wave & 3) * 8;
  const bf16_t* pA = Ab + (long)(bm + arow0 + lr) * K + cgs;
  const bf16_t* pB = Bb + (long)(bn + brow0 + lr) * K + cgs;

  // ds_read base offsets
  const int aoff = wr * 16384 + l15 * 128;          // + slot*65536 + mh*8192
  const int boff = 32768 + wc * 8192 + l15 * 128;   // + slot*65536 + nh*4096

  f32x4 acc[8][4] = {};
  bf16x8 afX[8], bfB[4], bf0[4];

  // ---- prologue: t0 full (8 instrs), then A0/B0(1) (4), B1/A1(1) (4) ----
  STAGE_A(0, 0, 0); STAGE_B(0, 0, 0); STAGE_B(0, 1, 0); STAGE_A(0, 1, 0);
  STAGE_A(1, 0, 64); STAGE_B(1, 0, 64);
  STAGE_B(1, 1, 64); STAGE_A(1, 1, 64);
  WVM8();   // tile0's 8 instrs landed
  SBAR();
  read_A(smem, aoff + 0, afX, xk0);   // A0(t0)
  read_B(smem, boff + 0, bf0, xk0);   // B0(t0)

  int slot = 0;
  for (int t = 0; t + 2 < NT; ++t) {
    const int so = slot * 65536, sn = (slot ^ 1) * 65536;
    const int k2 = (t + 2) << 6;
    // ---- P_a ----
    read_B(smem, so + boff + 4096, bfB, xk0);        // B1(t)
    STAGE_A(slot, 0, k2); STAGE_B(slot, 0, k2);      // A0(t+2), B0(t+2)
    SP1(); mfma_q<0, 0>(afX, bf0, acc); SP0();
    SP1(); mfma_q<0, 1>(afX, bfB, acc); SP0();
    read_A(smem, so + aoff + 8192, afX, xk0);        // A1(t)
    WVM8(); SBAR();                                  // c1
    // ---- P_b ----
    SP1(); mfma_q<1, 1>(afX, bfB, acc); SP0();
    SP1(); mfma_q<1, 0>(afX, bf0, acc); SP0();
    read_A(smem, sn + aoff + 0, afX, xk0);           // A0(t+1)
    read_B(smem, sn + boff + 0, bf0, xk0);           // B0(t+1)
    STAGE_B(slot, 1, k2); STAGE_A(slot, 1, k2);      // B1(t+2), A1(t+2)
    WVM8(); SBAR();                                  // c2
    slot ^= 1;
  }

  // ---- drain: tiles NT-2 (so), NT-1 (sn); no staging ----
  {
    const int so = slot * 65536, sn = (slot ^ 1) * 65536;
    read_B(smem, so + boff + 4096, bfB, xk0);        // B1(NT-2)
    SP1(); mfma_q<0, 0>(afX, bf0, acc); SP0();
    SP1(); mfma_q<0, 1>(afX, bfB, acc); SP0();
    read_A(smem, so + aoff + 8192, afX, xk0);        // A1(NT-2)
    WVM4(); SBAR();
    SP1(); mfma_q<1, 1>(afX, bfB, acc); SP0();
    SP1(); mfma_q<1, 0>(afX, bf0, acc); SP0();
    read_A(smem, sn + aoff + 0, afX, xk0);           // A0(NT-1)
    read_B(smem, sn + boff + 0, bf0, xk0);           // B0(NT-1)
    WVM0(); SBAR();
    // last tile
    read_B(smem, sn + boff + 4096, bfB, xk0);        // B1(NT-1)
    SP1(); mfma_q<0, 0>(afX, bf0, acc); SP0();
    SP1(); mfma_q<0, 1>(afX, bfB, acc); SP0();
    read_A(smem, sn + aoff + 8192, afX, xk0);        // A1(NT-1)
    SP1(); mfma_q<1, 1>(afX, bfB, acc); SP0();
    SP1(); mfma_q<1, 0>(afX, bf0, acc); SP0();
  }

  // ---- C-write: 4 rounds, double-buffered 64KB chunks, 1 barrier/round ----
  // (fully unrolled: acc/mask indices compile-time -- rule #20)
  float* eb0 = (float*)smem;
  float* eb1 = (float*)(smem + 65536);
  const int lrow = tid >> 3, t7 = tid & 7;
  const int growt0 = lrow + ((lrow >> 5) * 96);      // row map (wr0|wr1 halves)
  int4 m4a[8], m4b[8];
  if constexpr (MODE == 1) {
    const int* mrow = mask + bz * sMask + (long)(bm + growt0) * N + bn;
#pragma unroll
    for (int q = 0; q < 8; ++q)
      m4a[q] = *reinterpret_cast<const int4*>(mrow + (q * 8 + t7) * 4);
  }
  EWRITE(0, eb0);
  __syncthreads();
#pragma unroll
  for (int rd = 0; rd < 4; ++rd) {
    // prefetch next round's mask (uses the buffer NOT consumed this round)
    if constexpr (MODE == 1) {
      if (rd < 3) {
        const int* mrow =
            mask + bz * sMask + (long)(bm + (rd + 1) * 32 + growt0) * N + bn;
        if ((rd & 1) == 0) {
#pragma unroll
          for (int q = 0; q < 8; ++q)
            m4b[q] = *reinterpret_cast<const int4*>(mrow + (q * 8 + t7) * 4);
        } else {
#pragma unroll
          for (int q = 0; q < 8; ++q)
            m4a[q] = *reinterpret_cast<const int4*>(mrow + (q * 8 + t7) * 4);
        }
      }
    }
    // stage next round's acc into the other buffer (overlaps with emission)
    if (rd < 3) {
      if ((rd & 1) == 0) { EWRITE(rd + 1, eb1); } else { EWRITE(rd + 1, eb0); }
    }
    // emit this round from its buffer
    const float* eb = ((rd & 1) == 0) ? eb0 : eb1;
    const long rowbase = (long)(bm + rd * 32 + growt0) * N + bn;
#pragma unroll
    for (int q = 0; q < 8; ++q) {
      const int c4 = (q * 8 + t7) * 4;
      const f32x4 v = *reinterpret_cast<const f32x4*>(&eb[lrow * 256 + c4]);
      if constexpr (MODE == 1) {
        const int4 mq = ((rd & 1) == 0) ? m4a[q] : m4b[q];
        bf16x4 o;
        o[0] = (bf16_t)(mq.x ? __builtin_amdgcn_rcpf(1.f + __expf(-v[0])) : 0.f);
        o[1] = (bf16_t)(mq.y ? __builtin_amdgcn_rcpf(1.f + __expf(-v[1])) : 0.f);
        o[2] = (bf16_t)(mq.z ? __builtin_amdgcn_rcpf(1.f + __expf(-v[2])) : 0.f);
        o[3] = (bf16_t)(mq.w ? __builtin_amdgcn_rcpf(1.f + __expf(-v[3])) : 0.f);
        *reinterpret_cast<bf16x4*>((bf16_t*)Cp + bz * sC + rowbase + c4) = o;
      } else if constexpr (MODE == 0) {
        const f32x4 b4 = *reinterpret_cast<const f32x4*>(biasp + bn + c4);
        bf16x4 o;
        o[0] = (bf16_t)(v[0] + b4[0]); o[1] = (bf16_t)(v[1] + b4[1]);
        o[2] = (bf16_t)(v[2] + b4[2]); o[3] = (bf16_t)(v[3] + b4[3]);
        *reinterpret_cast<bf16x4*>((bf16_t*)Cp + bz * sC + rowbase + c4) = o;
      } else {
        *reinterpret_cast<f32x4*>((float*)Cp + bz * sC + rowbase + c4) = v;
      }
    }
    __syncthreads();   // protects: reads of this buffer done before rd+2 write
  }
}

extern "C" void kernel_launch(void* const* d_in, const int* in_sizes, int n_in,
                              void* d_out, int out_size, void* d_ws, size_t ws_size,
                              hipStream_t stream) {
  const float* queries = (const float*)d_in[0];
  const float* values  = (const float*)d_in[1];
  const int*   mask    = (const int*)d_in[2];
  const float* Wq = (const float*)d_in[3];
  const float* bq = (const float*)d_in[4];
  const float* Wk = (const float*)d_in[5];
  const float* bk = (const float*)d_in[6];
  const float* Wv = (const float*)d_in[7];
  const float* bv = (const float*)d_in[8];

  // B=8, L=2048, D=768. Workspace layout (bytes):
  char* ws = (char*)d_ws;
  bf16_t* qb  = (bf16_t*)(ws + 0);          // queries bf16   25165824
  bf16_t* vb  = (bf16_t*)(ws + 25165824);   // values bf16    25165824
  bf16_t* wqb = (bf16_t*)(ws + 50331648);   // Wq bf16         1179648
  bf16_t* wkb = (bf16_t*)(ws + 51511296);   // Wk bf16         1179648
  bf16_t* wvb = (bf16_t*)(ws + 52690944);   // Wv bf16         1179648
  bf16_t* qp  = (bf16_t*)(ws + 53870592);   // q_proj         25165824
  bf16_t* vp  = (bf16_t*)(ws + 79036416);   // v_proj         25165824
  bf16_t* kp  = (bf16_t*)(ws + 104202240);  // k_proj         25165824
  bf16_t* vpT = (bf16_t*)(ws + 129368064);  // v_proj^T       25165824
  bf16_t* P   = (bf16_t*)(ws + 154533888);  // sigmoid scores 67108864
  // total: 221642752

  // converts (q, v, 3 weights) in one launch, 4 float4/thread
  convert_kernel<<<6576, 256, 0, stream>>>(queries, values, Wq, Wk, Wv,
                                           qb, vb, wqb, wkb, wvb);

  const dim3 blk2(512);

  // q-proj & v-proj batched (independent): z=0 qb*Wq+bq->qp, z=1 vb*Wv+bv->vp
  gemm8p_kernel<0><<<dim3(64, 3, 2), blk2, 0, stream>>>(
      qb, wqb, bq, nullptr, qp, 16384, 768, 768, 0, 0, 0, 0,
      vb, wvb, bv, vp);
  // k-proj (faithful quirk: k = Linear_k(v_proj))
  gemm8p_kernel<0><<<dim3(64, 3, 1), blk2, 0, stream>>>(
      vp, wkb, bk, nullptr, kp, 16384, 768, 768, 0, 0, 0, 0,
      vp, wkb, bk, kp);

  // v_proj [b][2048][768] -> v_projT [b][768][2048]
  transpose_bf16_kernel<<<dim3(32, 12, 8), 256, 0, stream>>>(vp, vpT, 2048, 768);

  // P = sigmoid(mask(q k^T)) : per batch [2048,2048], K=768; int32 mask direct
  gemm8p_kernel<1><<<dim3(8, 8, 8), blk2, 0, stream>>>(
      qp, kp, nullptr, mask, P, 2048, 2048, 768,
      (long)2048 * 768, (long)2048 * 768, (long)2048 * 2048, (long)2048 * 2048,
      nullptr, nullptr, nullptr, nullptr);

  // context = P v : per batch [2048,768], K=2048, fp32 out
  gemm8p_kernel<2><<<dim3(8, 3, 8), blk2, 0, stream>>>(
      P, vpT, nullptr, nullptr, d_out, 2048, 768, 2048,
      (long)2048 * 2048, (long)768 * 2048, (long)2048 * 768, 0,
      nullptr, nullptr, nullptr, nullptr);
}